// Round 1
// baseline (1242.411 us; speedup 1.0000x reference)
//
#include <hip/hip_runtime.h>
#include <math.h>

// Problem constants (from reference)
#define B_    128
#define T_    2048
#define DIN   128
#define HID_  132
#define DOUT  64

// Tiling
#define TC    64            // time-steps (rows) per block in fused kernel
#define NC    (T_ / TC)     // 32 chunks
#define KB    44            // K-chunk staged into LDS (132 = 3*44)
#define NPAD  144           // padded N for W tile (16*9); 256 thr = 16 rowg x 16 colg of 4x9
#define ACT_STRIDE 145      // LDS act row stride (odd vs 32 banks -> conflict-free column reads)

// ---------------------------------------------------------------------------
// Kernel 1: per-chunk column max.  cmax[b][c][d] = max_{t in chunk c} P[b,t,d]
// ---------------------------------------------------------------------------
__global__ void chunkmax_kernel(const float* __restrict__ P, float* __restrict__ cmax) {
    int bid = blockIdx.x;
    int b = bid / NC, c = bid % NC;
    int d = threadIdx.x;                       // 0..127
    const float* p = P + ((size_t)(b * T_ + c * TC)) * DIN + d;
    float m = -INFINITY;
#pragma unroll 4
    for (int t = 0; t < TC; ++t) m = fmaxf(m, p[(size_t)t * DIN]);
    cmax[(size_t)(b * NC + c) * DIN + d] = m;
}

// ---------------------------------------------------------------------------
// Kernel 2: in-place suffix max over chunks: cmax[b][c][d] <- max_{c'>=c} cmax[b][c'][d]
// Each thread owns one (b,d) column -> no races.
// ---------------------------------------------------------------------------
__global__ void suffix_kernel(float* __restrict__ cmax) {
    int b = blockIdx.x;
    int d = threadIdx.x;                       // 0..127
    float run = -INFINITY;
    for (int c = NC - 1; c >= 0; --c) {
        size_t idx = (size_t)(b * NC + c) * DIN + d;
        run = fmaxf(run, cmax[idx]);
        cmax[idx] = run;
    }
}

// ---------------------------------------------------------------------------
// Fused main kernel: per (b, chunk): reverse cummax into LDS act buffer,
// then 4 MLP layers. Activations updated in place (regs -> barrier -> write).
// Thread tile: 4 rows x 9 cols; 16x16 thread-tile grid = 256 threads covers
// 64 rows x 144 cols (cols >= N are zero-padded weights -> exact zeros).
// ---------------------------------------------------------------------------
template <int K, int N, bool RELU, bool LAST>
__device__ __forceinline__ void gemm_layer(float* act, float* wt,
                                           const float* __restrict__ W,
                                           const float* __restrict__ bias,
                                           float* __restrict__ outg, int tid) {
    const int rg = tid >> 4;          // 0..15
    const int cg = tid & 15;          // 0..15
    const int r0 = rg * 4;
    const int j0 = cg * 9;

    float acc[4][9];
#pragma unroll
    for (int i = 0; i < 4; ++i)
#pragma unroll
        for (int u = 0; u < 9; ++u) acc[i][u] = 0.f;

    for (int kb = 0; kb < K; kb += KB) {
        const int kchunk = (K - kb < KB) ? (K - kb) : KB;
        __syncthreads();   // prior act writes visible / prior wt readers done
        // Stage W[kb:kb+kchunk][0:N] into LDS, zero-padded to NPAD cols.
        for (int idx = tid; idx < kchunk * NPAD; idx += 256) {
            int kk = idx / NPAD, j = idx % NPAD;
            wt[kk * NPAD + j] = (j < N) ? W[(size_t)(kb + kk) * N + j] : 0.f;
        }
        __syncthreads();
        for (int kk = 0; kk < kchunk; ++kk) {
            float a[4], w[9];
#pragma unroll
            for (int i = 0; i < 4; ++i) a[i] = act[(r0 + i) * ACT_STRIDE + kb + kk];
#pragma unroll
            for (int u = 0; u < 9; ++u) w[u] = wt[kk * NPAD + j0 + u];
#pragma unroll
            for (int i = 0; i < 4; ++i)
#pragma unroll
                for (int u = 0; u < 9; ++u) acc[i][u] = fmaf(a[i], w[u], acc[i][u]);
        }
    }
    __syncthreads();  // everyone's k-loop done before act is overwritten

    if (LAST) {
#pragma unroll
        for (int u = 0; u < 9; ++u) {
            int j = j0 + u;
            if (j < N) {
                float bv = bias[j];
#pragma unroll
                for (int i = 0; i < 4; ++i) {
                    float v = acc[i][u] + bv;
                    outg[(size_t)(r0 + i) * DOUT + j] = 1.f / (1.f + __expf(-5.f * v));
                }
            }
        }
    } else {
#pragma unroll
        for (int u = 0; u < 9; ++u) {
            int j = j0 + u;
            float bv = (j < N) ? bias[j] : 0.f;   // pad cols get exact 0
#pragma unroll
            for (int i = 0; i < 4; ++i) {
                float v = acc[i][u] + bv;
                if (RELU) v = fmaxf(v, 0.f);
                act[(r0 + i) * ACT_STRIDE + j] = v;
            }
        }
    }
}

__global__ __launch_bounds__(256, 2) void fused_kernel(
    const float* __restrict__ P, const float* __restrict__ csuf,
    const float* __restrict__ W1, const float* __restrict__ b1,
    const float* __restrict__ W2, const float* __restrict__ b2,
    const float* __restrict__ W3, const float* __restrict__ b3,
    const float* __restrict__ W4, const float* __restrict__ b4,
    float* __restrict__ Out) {
    __shared__ float act[TC * ACT_STRIDE];   // 37120 B
    __shared__ float wt[KB * NPAD];          // 25344 B  (total 62464 B < 64 KiB)

    const int bid = blockIdx.x;
    const int b = bid / NC, c = bid % NC;
    const int tid = threadIdx.x;

    // Phase B: reverse cummax for this chunk, seeded by suffix of later chunks.
    if (tid < DIN) {
        const int d = tid;
        float run = (c == NC - 1) ? -INFINITY
                                  : csuf[(size_t)(b * NC + c + 1) * DIN + d];
        const float* p = P + ((size_t)(b * T_ + c * TC)) * DIN + d;
        for (int t = TC - 1; t >= 0; --t) {
            run = fmaxf(run, p[(size_t)t * DIN]);
            act[t * ACT_STRIDE + d] = run;
        }
    }
    // (first gemm_layer k-chunk starts with __syncthreads())

    float* outg = Out + (size_t)(b * T_ + c * TC) * DOUT;
    gemm_layer<DIN, HID_, true, false>(act, wt, W1, b1, nullptr, tid);
    gemm_layer<HID_, HID_, true, false>(act, wt, W2, b2, nullptr, tid);
    gemm_layer<HID_, HID_, true, false>(act, wt, W3, b3, nullptr, tid);
    gemm_layer<HID_, DOUT, false, true>(act, wt, W4, b4, outg, tid);
}

// ---------------------------------------------------------------------------
extern "C" void kernel_launch(void* const* d_in, const int* in_sizes, int n_in,
                              void* d_out, int out_size, void* d_ws, size_t ws_size,
                              hipStream_t stream) {
    const float* P  = (const float*)d_in[0];
    const float* W1 = (const float*)d_in[1];
    const float* b1 = (const float*)d_in[2];
    const float* W2 = (const float*)d_in[3];
    const float* b2 = (const float*)d_in[4];
    const float* W3 = (const float*)d_in[5];
    const float* b3 = (const float*)d_in[6];
    const float* W4 = (const float*)d_in[7];
    const float* b4 = (const float*)d_in[8];
    float* out = (float*)d_out;

    // Workspace: chunk suffix maxima [B][NC][DIN] fp32 = 2 MiB
    float* cmax = (float*)d_ws;

    chunkmax_kernel<<<B_ * NC, DIN, 0, stream>>>(P, cmax);
    suffix_kernel<<<B_, DIN, 0, stream>>>(cmax);
    fused_kernel<<<B_ * NC, 256, 0, stream>>>(P, cmax, W1, b1, W2, b2, W3, b3,
                                              W4, b4, out);
}

// Round 2
// 371.766 us; speedup vs baseline: 3.3419x; 3.3419x over previous
//
#include <hip/hip_runtime.h>
#include <math.h>

// Problem constants
#define B_    128
#define T_    2048
#define DIN   128
#define HID_  132
#define DOUT  64

// Tiling
#define TC    128            // time-steps per fused block
#define NCC   (T_ / TC)      // 16 chunks
#define AS    168            // act row stride (f16 elems): 336B, 16B-aligned, 2-way banks (free)
#define WSTR  72             // wt chunk row stride (f16 elems): 144B, 16B-aligned, 2-way banks

typedef _Float16 half8   __attribute__((ext_vector_type(8)));
typedef _Float16 half4v  __attribute__((ext_vector_type(4)));
typedef float    float4v __attribute__((ext_vector_type(4)));

// ---------------------------------------------------------------------------
// Kernel 1: per-chunk column max
// ---------------------------------------------------------------------------
__global__ void chunkmax_kernel(const float* __restrict__ P, float* __restrict__ cmax) {
    int bid = blockIdx.x;
    int b = bid / NCC, c = bid % NCC;
    int d = threadIdx.x;                      // 0..127
    const float* p = P + ((size_t)(b * T_ + c * TC)) * DIN + d;
    float m = -INFINITY;
#pragma unroll 4
    for (int t = 0; t < TC; ++t) m = fmaxf(m, p[(size_t)t * DIN]);
    cmax[(size_t)(b * NCC + c) * DIN + d] = m;
}

// ---------------------------------------------------------------------------
// Kernel 2: in-place suffix max over chunks
// ---------------------------------------------------------------------------
__global__ void suffix_kernel(float* __restrict__ cmax) {
    int b = blockIdx.x, d = threadIdx.x;
    float run = -INFINITY;
    for (int c = NCC - 1; c >= 0; --c) {
        size_t idx = (size_t)(b * NCC + c) * DIN + d;
        run = fmaxf(run, cmax[idx]);
        cmax[idx] = run;
    }
}

// ---------------------------------------------------------------------------
// Kernel 3: weights -> f16, transposed [n][k], K zero-padded to mult of 32.
// Biases -> padded-to-144 f32.
// ---------------------------------------------------------------------------
__global__ void prep_kernel(const float* __restrict__ W1, const float* __restrict__ b1,
                            const float* __restrict__ W2, const float* __restrict__ b2,
                            const float* __restrict__ W3, const float* __restrict__ b3,
                            const float* __restrict__ W4, const float* __restrict__ b4,
                            _Float16* __restrict__ WT1, _Float16* __restrict__ WT2,
                            _Float16* __restrict__ WT3, _Float16* __restrict__ WT4,
                            float* __restrict__ bpad) {
    int l = blockIdx.x, tid = threadIdx.x;
    const float *W, *bs; _Float16* dst; int K, N, KP, R;
    if (l == 0)      { W = W1; bs = b1; dst = WT1; K = 128; N = 132; KP = 128; R = 144; }
    else if (l == 1) { W = W2; bs = b2; dst = WT2; K = 132; N = 132; KP = 160; R = 144; }
    else if (l == 2) { W = W3; bs = b3; dst = WT3; K = 132; N = 132; KP = 160; R = 144; }
    else             { W = W4; bs = b4; dst = WT4; K = 132; N = 64;  KP = 160; R = 64;  }
    int total = R * KP;
    for (int i = tid; i < total; i += 256) {
        int n = i / KP, k = i % KP;
        float v = (k < K && n < N) ? W[(size_t)k * N + n] : 0.f;
        dst[i] = (_Float16)v;
    }
    int NB = (l == 3) ? 64 : 132;
    for (int i = tid; i < 144; i += 256)
        bpad[l * 144 + i] = (i < NB) ? bs[i] : 0.f;
}

// ---------------------------------------------------------------------------
// One MLP layer via 16x16x32 f16 MFMA with swapped operands (D = W x act -> D^T).
// Wave w owns rows [32w, 32w+32); NT n-tiles of 16; K staged in 64-wide chunks.
// ---------------------------------------------------------------------------
template <int NT, int KTOT, bool LAST>
__device__ __forceinline__ void mlp_layer(const _Float16* __restrict__ WTg,
                                          const float* __restrict__ bp,
                                          _Float16* act, _Float16* wt,
                                          float* __restrict__ outg, int tid) {
    const int wave = tid >> 6, lane = tid & 63;
    const int quad = lane >> 4, l16 = lane & 15;
    float4v C0[NT], C1[NT];
#pragma unroll
    for (int nt = 0; nt < NT; ++nt) { C0[nt] = (float4v)0.0f; C1[nt] = (float4v)0.0f; }

    const int r0 = 32 * wave + l16;
    for (int kb = 0; kb < KTOT; kb += 64) {
        const int kc = (KTOT - kb < 64) ? (KTOT - kb) : 64;
        __syncthreads();   // prior readers of wt / writers of act done
        {   // stage WT rows [0, NT*16) cols [kb, kb+kc) -> wt (16B units)
            const int sh = (kc == 64) ? 3 : 2;         // units per row = kc/8
            const int upr = 1 << sh;
            const int total = NT * 16 * upr;
            for (int u = tid; u < total; u += 256) {
                int n = u >> sh, s = u & (upr - 1);
                *(uint4*)(wt + n * WSTR + s * 8) =
                    *(const uint4*)(WTg + (size_t)n * KTOT + kb + s * 8);
            }
        }
        __syncthreads();
        for (int kt = 0; kt < kc; kt += 32) {
            const int ko = kb + kt + quad * 8;
            half8 a0 = *(const half8*)(act + (size_t)r0 * AS + ko);
            half8 a1 = *(const half8*)(act + (size_t)(r0 + 16) * AS + ko);
#pragma unroll
            for (int nt = 0; nt < NT; ++nt) {
                half8 w = *(const half8*)(wt + (nt * 16 + l16) * WSTR + kt + quad * 8);
                C0[nt] = __builtin_amdgcn_mfma_f32_16x16x32_f16(w, a0, C0[nt], 0, 0, 0);
                C1[nt] = __builtin_amdgcn_mfma_f32_16x16x32_f16(w, a1, C1[nt], 0, 0, 0);
            }
        }
    }
    __syncthreads();   // all act reads done before in-place overwrite
#pragma unroll
    for (int s = 0; s < 2; ++s) {
        const int m = 32 * wave + s * 16 + l16;
#pragma unroll
        for (int nt = 0; nt < NT; ++nt) {
            const int n0 = nt * 16 + quad * 4;
            float4v c = s ? C1[nt] : C0[nt];
            float4v bv = *(const float4v*)(bp + n0);
            if (LAST) {
                float4v o;
#pragma unroll
                for (int r = 0; r < 4; ++r)
                    o[r] = 1.f / (1.f + __expf(-5.f * (c[r] + bv[r])));
                *(float4v*)(outg + (size_t)m * DOUT + n0) = o;
            } else {
                half4v h;
#pragma unroll
                for (int r = 0; r < 4; ++r)
                    h[r] = (_Float16)fmaxf(c[r] + bv[r], 0.f);
                *(half4v*)(act + (size_t)m * AS + n0) = h;
            }
        }
    }
    // next layer's first __syncthreads() orders these writes vs. its reads
}

// ---------------------------------------------------------------------------
// Fused kernel: reverse cummax (2 parallel segments + merge) -> 4 MFMA layers
// ---------------------------------------------------------------------------
__global__ __launch_bounds__(256, 2) void fused_kernel(
    const float* __restrict__ P, const float* __restrict__ csuf,
    const _Float16* __restrict__ WT1, const _Float16* __restrict__ WT2,
    const _Float16* __restrict__ WT3, const _Float16* __restrict__ WT4,
    const float* __restrict__ bpad, float* __restrict__ Out) {
    __shared__ _Float16 act[TC * AS];     // 43008 B
    __shared__ _Float16 wt[144 * WSTR];   // 20736 B  (total 63744 <= 64 KiB)

    const int bid = blockIdx.x;
    const int b = bid / NCC, c = bid % NCC;
    const int tid = threadIdx.x;

    {   // zero K-pad cols [144,160) once (read by layers 2-4; W rows there are 0,
        // but LDS garbage could be NaN -> 0*NaN)
        const int m = tid >> 1, s2 = tid & 1;
        uint4 z{0, 0, 0, 0};
        *(uint4*)(act + (size_t)m * AS + 144 + s2 * 8) = z;
    }
    {   // reverse cummax: 2 threads per column (halves of 64 t), then merge
        const int d = tid & 127, hf = tid >> 7;
        float run = -INFINITY;
        if (hf == 1 && c != NCC - 1) run = csuf[(size_t)(b * NCC + c + 1) * DIN + d];
        const float* p = P + ((size_t)(b * T_ + c * TC + hf * 64)) * DIN + d;
#pragma unroll 4
        for (int t = 63; t >= 0; --t) {
            run = fmaxf(run, p[(size_t)t * DIN]);
            act[(size_t)(hf * 64 + t) * AS + d] = (_Float16)run;
        }
        __syncthreads();
        if (hf == 0) {   // fold suffix of later half (act[64][d]) into first half
            const _Float16 mx = act[(size_t)64 * AS + d];
            for (int t = 0; t < 64; ++t) {
                _Float16 v = act[(size_t)t * AS + d];
                act[(size_t)t * AS + d] = (v > mx) ? v : mx;
            }
        }
    }

    float* outg = Out + (size_t)(b * T_ + c * TC) * DOUT;
    mlp_layer<9, 128, false>(WT1, bpad,        act, wt, nullptr, tid);
    mlp_layer<9, 160, false>(WT2, bpad + 144,  act, wt, nullptr, tid);
    mlp_layer<9, 160, false>(WT3, bpad + 288,  act, wt, nullptr, tid);
    mlp_layer<4, 160, true >(WT4, bpad + 432,  act, wt, outg,    tid);
}

// ---------------------------------------------------------------------------
extern "C" void kernel_launch(void* const* d_in, const int* in_sizes, int n_in,
                              void* d_out, int out_size, void* d_ws, size_t ws_size,
                              hipStream_t stream) {
    const float* P  = (const float*)d_in[0];
    const float* W1 = (const float*)d_in[1];
    const float* b1 = (const float*)d_in[2];
    const float* W2 = (const float*)d_in[3];
    const float* b2 = (const float*)d_in[4];
    const float* W3 = (const float*)d_in[5];
    const float* b3 = (const float*)d_in[6];
    const float* W4 = (const float*)d_in[7];
    const float* b4 = (const float*)d_in[8];
    float* out = (float*)d_out;

    // ws layout
    char* ws = (char*)d_ws;
    float*    cmax = (float*)ws;                          // 128*16*128*4 = 1 MiB
    _Float16* WT1  = (_Float16*)(ws + (1 << 20));         // 144*128 f16
    _Float16* WT2  = WT1 + 144 * 128;                     // 144*160
    _Float16* WT3  = WT2 + 144 * 160;                     // 144*160
    _Float16* WT4  = WT3 + 144 * 160;                     // 64*160
    float*    bpad = (float*)(WT4 + 64 * 160);            // 4*144 f32 (16B-aligned)

    chunkmax_kernel<<<B_ * NCC, DIN, 0, stream>>>(P, cmax);
    suffix_kernel<<<B_, DIN, 0, stream>>>(cmax);
    prep_kernel<<<4, 256, 0, stream>>>(W1, b1, W2, b2, W3, b3, W4, b4,
                                       WT1, WT2, WT3, WT4, bpad);
    fused_kernel<<<B_ * NCC, 256, 0, stream>>>(P, cmax, WT1, WT2, WT3, WT4,
                                               bpad, out);
}

// Round 3
// 334.585 us; speedup vs baseline: 3.7133x; 1.1111x over previous
//
#include <hip/hip_runtime.h>
#include <math.h>

// Problem constants
#define B_    128
#define T_    2048
#define DIN   128
#define HID_  132
#define DOUT  64

// Tiling
#define TC    128            // time-steps per fused block
#define NCC   (T_ / TC)      // 16 chunks
#define AS    168            // act row stride (f16): 336B = 16B-aligned, 20-banks offset (2-way, free)
#define WSTR  72             // wt row stride (f16): 144B = 16B-aligned, 4-banks offset (2-way, free)

typedef _Float16 half8   __attribute__((ext_vector_type(8)));
typedef _Float16 half4v  __attribute__((ext_vector_type(4)));
typedef float    float4v __attribute__((ext_vector_type(4)));

// ---------------------------------------------------------------------------
// Kernel 1: blocks [0,2048): per-chunk column max of P.
//           blocks [2048,2080): weight->f16 transpose prep (coalesced reads,
//           tiny scattered 2B stores; 8 slice-blocks per layer).
// ---------------------------------------------------------------------------
__global__ __launch_bounds__(256) void prep_chunkmax_kernel(
    const float* __restrict__ P,
    const float* __restrict__ W1, const float* __restrict__ b1,
    const float* __restrict__ W2, const float* __restrict__ b2,
    const float* __restrict__ W3, const float* __restrict__ b3,
    const float* __restrict__ W4, const float* __restrict__ b4,
    float* __restrict__ cmax,
    _Float16* __restrict__ WT1, _Float16* __restrict__ WT2,
    _Float16* __restrict__ WT3, _Float16* __restrict__ WT4,
    float* __restrict__ bpad) {
    const int bid = blockIdx.x;
    const int tid = threadIdx.x;
    if (bid < B_ * NCC) {
        // ---- chunk max: 256 threads = (d 0..127) x (half 0..1) ----
        __shared__ float part[256];
        const int b = bid >> 4, c = bid & 15;
        const int d = tid & 127, h = tid >> 7;
        const float* p = P + ((size_t)(b * T_ + c * TC + h * 64)) * DIN + d;
        float m = -INFINITY;
#pragma unroll 4
        for (int t = 0; t < 64; ++t) m = fmaxf(m, p[(size_t)t * DIN]);
        part[tid] = m;
        __syncthreads();
        if (h == 0)
            cmax[((size_t)b * NCC + c) * DIN + d] = fmaxf(part[d], part[128 + d]);
    } else {
        // ---- weight prep ----
        const int pb = bid - B_ * NCC;
        const int l = pb >> 3, slice = pb & 7;
        const float *W, *bs; _Float16* dst; int K, N, KP, R, NB;
        if (l == 0)      { W = W1; bs = b1; dst = WT1; K = 128; N = 132; KP = 128; R = 144; NB = 132; }
        else if (l == 1) { W = W2; bs = b2; dst = WT2; K = 132; N = 132; KP = 160; R = 144; NB = 132; }
        else if (l == 2) { W = W3; bs = b3; dst = WT3; K = 132; N = 132; KP = 160; R = 144; NB = 132; }
        else             { W = W4; bs = b4; dst = WT4; K = 132; N = 64;  KP = 160; R = 64;  NB = 64;  }
        // k-rows k ≡ slice (mod 8); coalesced read of W[k][*], scatter-store f16
        for (int k = slice; k < KP; k += 8) {
            for (int n = tid; n < R; n += 256) {
                float v = (k < K && n < N) ? W[(size_t)k * N + n] : 0.f;
                dst[(size_t)n * KP + k] = (_Float16)v;
            }
        }
        if (slice == 0)
            for (int i = tid; i < 144; i += 256)
                bpad[l * 144 + i] = (i < NB) ? bs[i] : 0.f;
    }
}

// ---------------------------------------------------------------------------
// One MLP layer via 16x16x32 f16 MFMA, swapped operands (D = W x act -> D^T).
// 2x2 wave split: wave (mh,jh): rows [64*mh, 64*mh+64) as 4 strips of 16,
// n-tiles with parity jh. Per k-step: 4 a-reads + <=5 w-reads feed <=20 MFMAs.
// ---------------------------------------------------------------------------
template <int NTILES, int KTOT, bool LAST>
__device__ __forceinline__ void mlp_layer(const _Float16* __restrict__ WTg,
                                          const float* __restrict__ bp,
                                          _Float16* act, _Float16* wt,
                                          float* __restrict__ outg, int tid) {
    const int wave = tid >> 6, lane = tid & 63;
    const int quad = lane >> 4, l16 = lane & 15;
    const int mh = wave >> 1, jh = wave & 1;
    constexpr int UMAX = (NTILES + 1) / 2;

    float4v C[4][UMAX];
#pragma unroll
    for (int s = 0; s < 4; ++s)
#pragma unroll
        for (int u = 0; u < UMAX; ++u) C[s][u] = (float4v)0.0f;

    const int r0 = 64 * mh + l16;
    for (int kb = 0; kb < KTOT; kb += 64) {
        const int kc = (KTOT - kb < 64) ? (KTOT - kb) : 64;
        __syncthreads();   // prior wt readers / act writers done
        {   // stage WT rows [0, NTILES*16) cols [kb, kb+kc) in 16B units
            const int sh = (kc == 64) ? 3 : 2;
            const int upr = 1 << sh;
            const int total = NTILES * 16 * upr;
            for (int u = tid; u < total; u += 256) {
                int n = u >> sh, s = u & (upr - 1);
                *(uint4*)(wt + n * WSTR + s * 8) =
                    *(const uint4*)(WTg + (size_t)n * KTOT + kb + s * 8);
            }
        }
        __syncthreads();
        for (int kt = 0; kt < kc; kt += 32) {
            const int ko = kb + kt + quad * 8;
            half8 a[4];
#pragma unroll
            for (int s = 0; s < 4; ++s)
                a[s] = *(const half8*)(act + (size_t)(r0 + 16 * s) * AS + ko);
#pragma unroll
            for (int u = 0; u < UMAX; ++u) {
                const int nt = jh + 2 * u;
                if (nt < NTILES) {
                    half8 w = *(const half8*)(wt + (nt * 16 + l16) * WSTR + kt + quad * 8);
#pragma unroll
                    for (int s = 0; s < 4; ++s)
                        C[s][u] = __builtin_amdgcn_mfma_f32_16x16x32_f16(w, a[s], C[s][u], 0, 0, 0);
                }
            }
        }
    }
    __syncthreads();   // all act reads done before in-place overwrite
#pragma unroll
    for (int s = 0; s < 4; ++s) {
        const int m = 64 * mh + 16 * s + l16;
#pragma unroll
        for (int u = 0; u < UMAX; ++u) {
            const int nt = jh + 2 * u;
            if (nt < NTILES) {
                const int n0 = nt * 16 + quad * 4;
                float4v c = C[s][u];
                float4v bv = *(const float4v*)(bp + n0);
                if (LAST) {
                    float4v o;
#pragma unroll
                    for (int r = 0; r < 4; ++r)
                        o[r] = 1.f / (1.f + __expf(-5.f * (c[r] + bv[r])));
                    *(float4v*)(outg + (size_t)m * DOUT + n0) = o;
                } else {
                    half4v hv;
#pragma unroll
                    for (int r = 0; r < 4; ++r)
                        hv[r] = (_Float16)fmaxf(c[r] + bv[r], 0.f);
                    *(half4v*)(act + (size_t)m * AS + n0) = hv;
                }
            }
        }
    }
    // next layer's first __syncthreads() orders these writes vs. its reads
}

// ---------------------------------------------------------------------------
// Fused kernel: tail-suffix from cmax + reverse cummax -> 4 MFMA layers
// ---------------------------------------------------------------------------
__global__ __launch_bounds__(256, 2) void fused_kernel(
    const float* __restrict__ P, const float* __restrict__ cmax,
    const _Float16* __restrict__ WT1, const _Float16* __restrict__ WT2,
    const _Float16* __restrict__ WT3, const _Float16* __restrict__ WT4,
    const float* __restrict__ bpad, float* __restrict__ Out) {
    __shared__ _Float16 act[TC * AS];     // 43008 B
    __shared__ _Float16 wt[144 * WSTR];   // 20736 B  (total 63744 <= 64 KiB)

    const int bid = blockIdx.x;
    const int b = bid / NCC, c = bid % NCC;
    const int tid = threadIdx.x;

    {   // zero K-pad cols [144,160) once (read by layers 2-4)
        const int m = tid >> 1, s2 = tid & 1;
        uint4 z{0, 0, 0, 0};
        *(uint4*)(act + (size_t)m * AS + 144 + s2 * 8) = z;
    }
    {   // reverse cummax, 2 threads per column; hf==1 seeds from later-chunk maxima
        const int d = tid & 127, hf = tid >> 7;
        float run = -INFINITY;
        if (hf == 1)
            for (int j = c + 1; j < NCC; ++j)
                run = fmaxf(run, cmax[((size_t)b * NCC + j) * DIN + d]);
        const float* p = P + ((size_t)(b * T_ + c * TC + hf * 64)) * DIN + d;
#pragma unroll 4
        for (int t = 63; t >= 0; --t) {
            run = fmaxf(run, p[(size_t)t * DIN]);
            act[(size_t)(hf * 64 + t) * AS + d] = (_Float16)run;
        }
        __syncthreads();
        if (hf == 0) {   // fold suffix of later half into first half
            const _Float16 mx = act[(size_t)64 * AS + d];
            for (int t = 0; t < 64; ++t) {
                _Float16 v = act[(size_t)t * AS + d];
                act[(size_t)t * AS + d] = (v > mx) ? v : mx;
            }
        }
    }

    float* outg = Out + (size_t)(b * T_ + c * TC) * DOUT;
    mlp_layer<9, 128, false>(WT1, bpad,       act, wt, nullptr, tid);
    mlp_layer<9, 160, false>(WT2, bpad + 144, act, wt, nullptr, tid);
    mlp_layer<9, 160, false>(WT3, bpad + 288, act, wt, nullptr, tid);
    mlp_layer<4, 160, true >(WT4, bpad + 432, act, wt, outg,    tid);
}

// ---------------------------------------------------------------------------
extern "C" void kernel_launch(void* const* d_in, const int* in_sizes, int n_in,
                              void* d_out, int out_size, void* d_ws, size_t ws_size,
                              hipStream_t stream) {
    const float* P  = (const float*)d_in[0];
    const float* W1 = (const float*)d_in[1];
    const float* b1 = (const float*)d_in[2];
    const float* W2 = (const float*)d_in[3];
    const float* b2 = (const float*)d_in[4];
    const float* W3 = (const float*)d_in[5];
    const float* b3 = (const float*)d_in[6];
    const float* W4 = (const float*)d_in[7];
    const float* b4 = (const float*)d_in[8];
    float* out = (float*)d_out;

    // ws layout
    char* ws = (char*)d_ws;
    float*    cmax = (float*)ws;                          // 128*16*128*4 = 1 MiB
    _Float16* WT1  = (_Float16*)(ws + (1 << 20));         // 144*128 f16
    _Float16* WT2  = WT1 + 144 * 128;                     // 144*160
    _Float16* WT3  = WT2 + 144 * 160;                     // 144*160
    _Float16* WT4  = WT3 + 144 * 160;                     // 64*160
    float*    bpad = (float*)(WT4 + 64 * 160);            // 4*144 f32 (16B-aligned)

    prep_chunkmax_kernel<<<B_ * NCC + 32, 256, 0, stream>>>(
        P, W1, b1, W2, b2, W3, b3, W4, b4, cmax, WT1, WT2, WT3, WT4, bpad);
    fused_kernel<<<B_ * NCC, 256, 0, stream>>>(P, cmax, WT1, WT2, WT3, WT4,
                                               bpad, out);
}